// Round 5
// baseline (341.152 us; speedup 1.0000x reference)
//
#include <hip/hip_runtime.h>
#include <hip/hip_bf16.h>

// SpatialAttention: B=4, H=W=64, C=D=256. N=4096 tokens/batch.
// fp32->bf16, QKV proj (MFMA, W staged in LDS), split-K flash attn with
// SWAPPED QK. v5 = v1's proven inner loop (BM=64, BN=32, 4 waves,
// global_load_lds K dbuf, 2 barriers/iter) + cvt_pk P packing, with THREE
// placement changes: (1) XCD cohort swizzle on k_attn so each XCD's L2
// holds its cohorts' 1 MB K/V slabs (loads drop from L3 ~600cy to L2
// ~200cy latency); (2) nks=4 -> 1024 blocks = 4 independent blocks/CU;
// (3) same swizzle on proj3 (xb slab reuse) and oproj (partial-row reuse).
// No-max softmax => unnormalized partials; combine folded into out-proj.
// v5b: identical to v5 except k_oproj's partial pointers are statically
// unrolled (no runtime-indexed pointer array -> no scratch).

typedef __attribute__((ext_vector_type(8))) short short8;
typedef __attribute__((ext_vector_type(4))) short short4v;
typedef __attribute__((ext_vector_type(4))) float floatx4;

#define NB 4
#define NT 4096
#define CD 256
#define MTOT (NB * NT)   // 16384

__device__ __forceinline__ short bf16s(float f) {
    union { float f; unsigned u; } a; a.f = f;
    unsigned u = a.u;
    return (short)((u + 0x7fffu + ((u >> 16) & 1u)) >> 16);   // RNE
}

__device__ __forceinline__ float bf2f(short s) {
    union { unsigned u; float f; } a;
    a.u = ((unsigned)(unsigned short)s) << 16;
    return a.f;
}

__device__ __forceinline__ short8 ld8(const short* p) {
    return *(const short8*)p;
}

__device__ __forceinline__ floatx4 mfma16(short8 a, short8 b, floatx4 c) {
    return __builtin_amdgcn_mfma_f32_16x16x32_bf16(a, b, c, 0, 0, 0);
}

// async global->LDS DMA, 16 B/lane; LDS dest = wave-uniform base + lane*16
__device__ __forceinline__ void dma16(const void* g, void* l) {
    __builtin_amdgcn_global_load_lds(
        (const __attribute__((address_space(1))) void*)g,
        (__attribute__((address_space(3))) void*)l, 16, 0, 0);
}

// ---- convert features fp32 -> bf16 [16384 x 256] row-major ----
__global__ __launch_bounds__(256) void k_convx(const float* __restrict__ x,
                                               short* __restrict__ xb) {
    int i = (blockIdx.x * 256 + threadIdx.x) * 4;
    float4 v = *(const float4*)(x + i);
    short4v o;
    o.x = bf16s(v.x); o.y = bf16s(v.y); o.z = bf16s(v.z); o.w = bf16s(v.w);
    *(short4v*)(xb + i) = o;
}

// ---- convert + transpose weights: Wt[z][n][c] = W_z[c][n], bf16 ----
__global__ __launch_bounds__(256) void k_convw(const float* __restrict__ w0,
                                               const float* __restrict__ w1,
                                               const float* __restrict__ w2,
                                               const float* __restrict__ w3,
                                               short* __restrict__ wt) {
    int z = blockIdx.y;
    const float* w = (z == 0) ? w0 : (z == 1) ? w1 : (z == 2) ? w2 : w3;
    int c = blockIdx.x;
    int n = threadIdx.x;
    wt[z * 65536 + n * 256 + c] = bf16s(w[c * 256 + n]);
}

// ---- fused QKV projection: 1536 blocks 1-D, XCD-swizzled so the 12
// blocks (3 z x 4 y) sharing one 128-row xb slab land on one XCD ----
__global__ __launch_bounds__(256) void k_proj3(const short* __restrict__ A,
                                               const short* __restrict__ Wt,
                                               const float* __restrict__ bq,
                                               const float* __restrict__ bk,
                                               const float* __restrict__ bv,
                                               short* __restrict__ Qb,
                                               short* __restrict__ Kb,
                                               short* __restrict__ Vt) {
    __shared__ __align__(16) short Ws[16384];
    int blk = blockIdx.x;                       // 1536 blocks
    int wk = (blk & 7) * 192 + (blk >> 3);      // xcd = blk%8 gets work chunk
    int m = wk / 12, rest = wk - m * 12;        // work = m*12 + z*4 + y
    int z = rest >> 2, y = rest & 3;
    const short* W = Wt + z * 65536;
    const float* bias = (z == 0) ? bq : (z == 1) ? bk : bv;
    float scale = (z == 0) ? 0.0625f : 1.0f;   // fold 1/sqrt(256) into Q
    int m0 = m * 128;
    int n0 = y * 64;
    int tid = threadIdx.x;
    int w = tid >> 6, l = tid & 63, r = l & 15, q = l >> 4;

#pragma unroll
    for (int cg = 0; cg < 8; ++cg)
        dma16(W + (size_t)(n0 + w * 16 + r) * CD + (cg * 4 + q) * 8,
              &Ws[w * 4096 + cg * 512]);
    __syncthreads();

    const short* a0 = A + (size_t)(m0 + w * 32 + r) * CD;
    const short* a1 = a0 + 16 * CD;
    floatx4 acc[2][4];
#pragma unroll
    for (int rt = 0; rt < 2; ++rt)
#pragma unroll
        for (int j = 0; j < 4; ++j) acc[rt][j] = (floatx4){0.f, 0.f, 0.f, 0.f};
#pragma unroll
    for (int c = 0; c < 8; ++c) {
        short8 af0 = ld8(a0 + c * 32 + q * 8);
        short8 af1 = ld8(a1 + c * 32 + q * 8);
#pragma unroll
        for (int j = 0; j < 4; ++j) {
            short8 wf = ld8(&Ws[j * 4096 + c * 512 + l * 8]);
            acc[0][j] = mfma16(af0, wf, acc[0][j]);
            acc[1][j] = mfma16(af1, wf, acc[1][j]);
        }
    }
#pragma unroll
    for (int rt = 0; rt < 2; ++rt)
#pragma unroll
        for (int j = 0; j < 4; ++j) {
            int col = n0 + j * 16 + r;
            float bvv = bias[col];
#pragma unroll
            for (int i = 0; i < 4; ++i) {
                int row = m0 + w * 32 + rt * 16 + q * 4 + i;
                short s = bf16s((acc[rt][j][i] + bvv) * scale);
                if (z == 0) Qb[(size_t)row * CD + col] = s;
                else if (z == 1) Kb[(size_t)row * CD + col] = s;
                else {
                    int bb = row >> 12, lm = row & (NT - 1);
                    Vt[((size_t)bb * CD + col) * NT + lm] = s;
                }
            }
        }
}

// ---- split-K flash attention v5: v1 loop, 1-D XCD-swizzled grid ----
// Works ordered cohort-major: work = (b*nks+ks)*64 + x, so each XCD owns
// whole cohorts; a cohort's 64 blocks stream the SAME 0.5 MB K-slab and
// 0.5 MB V-slab in the same iteration order -> L2-resident KV.
__global__ __launch_bounds__(256, 4) void k_attn(const short* __restrict__ Qb,
                                                 const short* __restrict__ Kb,
                                                 const short* __restrict__ Vt,
                                                 short* __restrict__ Op0,
                                                 short* __restrict__ Op1,
                                                 short* __restrict__ Op2,
                                                 short* __restrict__ Op3,
                                                 float* __restrict__ Lp,
                                                 int nks) {
    __shared__ __align__(16) short Ks[2][8192];   // 2 x 16 KB
    __shared__ __align__(16) short P[64][36];     // [row][tok], pad 4

    const int tid = threadIdx.x;
    const int w = tid >> 6;
    const int l = tid & 63;
    const int r = l & 15, q = l >> 4;
    // 1-D swizzled decode: nbk = 64*NB*nks, nbk % 8 == 0 -> bijective
    const int nbk = gridDim.x;
    const int blk = blockIdx.x;
    const int wk = (blk & 7) * (nbk >> 3) + (blk >> 3);
    const int bx = wk & 63;          // x fastest within cohort
    const int co = wk >> 6;          // cohort = b*nks + ks
    const int b = co / nks;
    const int ks = co - b * nks;
    const int m0 = bx * 64;
    // token range: 128 units of 32 tokens split across nks
    const int qq = 128 / nks, rem = 128 % nks;
    const int u0 = ks * qq + (ks < rem ? ks : rem);
    const int cnt = qq + (ks < rem ? 1 : 0);
    const int t0 = u0 * 32;
    const int tt_d = w & 1;               // DMA token-subtile
    const int cb_d = (w >> 1) * 4;        // DMA chunk-group base
    const short* Qp = Qb + (size_t)b * NT * CD;
    const short* Kp = Kb + (size_t)b * NT * CD;
    const short* Vp = Vt + (size_t)b * CD * NT;   // [256][4096]
    short* Op = (ks == 0) ? Op0 : (ks == 1) ? Op1 : (ks == 2) ? Op2 : Op3;

    // Q fragments (B-operand): rows m0 + w*16 + r, Q pre-scaled by 1/16
    short8 qf[8];
#pragma unroll
    for (int c = 0; c < 8; ++c)
        qf[c] = ld8(Qp + (size_t)(m0 + w * 16 + r) * CD + c * 32 + q * 8);

    floatx4 o[4][4];
#pragma unroll
    for (int rt = 0; rt < 4; ++rt)
#pragma unroll
        for (int dt = 0; dt < 4; ++dt) o[rt][dt] = (floatx4){0.f, 0.f, 0.f, 0.f};
    float ls = 0.f;

    // prologue: DMA K tile 0 into Ks[0]
#pragma unroll
    for (int j = 0; j < 4; ++j)
        dma16(Kp + (size_t)(t0 + tt_d * 16 + r) * CD + ((cb_d + j) * 4 + q) * 8,
              &Ks[0][tt_d * 4096 + (cb_d + j) * 512]);

#pragma unroll 1
    for (int it = 0; it < cnt; ++it) {
        const int p = it & 1;
        const int n0 = t0 + it * 32;
        __syncthreads();   // drains vmcnt(0): Ks[p] DMA complete, P consumed

        // V fragments for THIS iter (before next DMA so their wait leaves DMA in flight)
        short8 vf[4];
#pragma unroll
        for (int dt = 0; dt < 4; ++dt)
            vf[dt] = ld8(Vp + (size_t)(w * 64 + dt * 16 + r) * NT + n0 + q * 8);

        if (it + 1 < cnt) {
#pragma unroll
            for (int j = 0; j < 4; ++j)
                dma16(Kp + (size_t)(n0 + 32 + tt_d * 16 + r) * CD + ((cb_d + j) * 4 + q) * 8,
                      &Ks[1 - p][tt_d * 4096 + (cb_d + j) * 512]);
        }

        // QK swapped: S^T tiles; lane (r,q) reg i = S[row m0+w*16+r][tok n0+tt*16+q*4+i]
        floatx4 s0 = {0.f, 0.f, 0.f, 0.f};
        floatx4 s1 = {0.f, 0.f, 0.f, 0.f};
#pragma unroll
        for (int c = 0; c < 8; ++c) {
            s0 = mfma16(ld8(&Ks[p][c * 512 + l * 8]), qf[c], s0);
            s1 = mfma16(ld8(&Ks[p][4096 + c * 512 + l * 8]), qf[c], s1);
        }

        // exp + scalar lsum + packed cvt_pk b64 P writes (4 bf16 each)
#pragma unroll
        for (int tt = 0; tt < 2; ++tt) {
            floatx4 sv = tt ? s1 : s0;
            float e0 = __expf(sv[0]), e1 = __expf(sv[1]);
            float e2 = __expf(sv[2]), e3 = __expf(sv[3]);
            ls += (e0 + e1) + (e2 + e3);
            unsigned pk01, pk23;
            asm("v_cvt_pk_bf16_f32 %0, %1, %2" : "=v"(pk01) : "v"(e0), "v"(e1));
            asm("v_cvt_pk_bf16_f32 %0, %1, %2" : "=v"(pk23) : "v"(e2), "v"(e3));
            uint2 pk; pk.x = pk01; pk.y = pk23;
            *(uint2*)&P[w * 16 + r][tt * 16 + q * 4] = pk;
        }
        // P visible block-wide; NOT __syncthreads (would drain the K DMA)
        asm volatile("s_waitcnt lgkmcnt(0)\n\ts_barrier" ::: "memory");

        // PV: o[rt][dt] += P[rt rows][tok] x V[d-slice][tok]
#pragma unroll
        for (int rt = 0; rt < 4; ++rt) {
            short8 pf = ld8(&P[rt * 16 + r][q * 8]);
#pragma unroll
            for (int dt = 0; dt < 4; ++dt)
                o[rt][dt] = mfma16(pf, vf[dt], o[rt][dt]);
        }
    }

    // partial lsum: lane (r,q) holds row m0+w*16+r partial; reduce across q
    ls += __shfl_xor(ls, 16);
    ls += __shfl_xor(ls, 32);
    if (l < 16)
        Lp[(size_t)ks * MTOT + b * NT + m0 + w * 16 + l] = ls;

    // unnormalized partial O store (cols w*64..+64, all 64 rows)
#pragma unroll
    for (int rt = 0; rt < 4; ++rt)
#pragma unroll
        for (int i = 0; i < 4; ++i) {
            int row = m0 + rt * 16 + q * 4 + i;
#pragma unroll
            for (int dt = 0; dt < 4; ++dt)
                Op[((size_t)b * NT + row) * CD + w * 64 + dt * 16 + r] =
                    bf16s(o[rt][dt][i]);
        }
}

// ---- output projection + split-K combine: A = (sum Opk)/(sum lk), fp32 out
// 512 blocks 1-D, XCD-swizzled so the 4 y-blocks sharing one 128-row
// partial slab land on one XCD (partials read from L2 after first touch).
__global__ __launch_bounds__(256) void k_oproj(const short* __restrict__ Op0,
                                               const short* __restrict__ Op1,
                                               const short* __restrict__ Op2,
                                               const short* __restrict__ Op3,
                                               const float* __restrict__ Lp,
                                               const short* __restrict__ Wot,
                                               const float* __restrict__ bo,
                                               float* __restrict__ out, int nks) {
    __shared__ __align__(16) short Ws[16384];
    int blk = blockIdx.x;                       // 512 blocks
    int wk = (blk & 7) * 64 + (blk >> 3);       // work = m*4 + y
    int m0 = (wk >> 2) * 128;
    int n0 = (wk & 3) * 64;
    int tid = threadIdx.x;
    int w = tid >> 6, l = tid & 63, r = l & 15, q = l >> 4;

#pragma unroll
    for (int cg = 0; cg < 8; ++cg)
        dma16(Wot + (size_t)(n0 + w * 16 + r) * CD + (cg * 4 + q) * 8,
              &Ws[w * 4096 + cg * 512]);
    __syncthreads();

    int row0 = m0 + w * 32 + r;
    float lt0 = Lp[row0] + Lp[MTOT + row0];
    float lt1 = Lp[row0 + 16] + Lp[MTOT + row0 + 16];
    if (nks >= 3) { lt0 += Lp[2 * (size_t)MTOT + row0]; lt1 += Lp[2 * (size_t)MTOT + row0 + 16]; }
    if (nks >= 4) { lt0 += Lp[3 * (size_t)MTOT + row0]; lt1 += Lp[3 * (size_t)MTOT + row0 + 16]; }
    float inv0 = 1.0f / lt0, inv1 = 1.0f / lt1;
    const short* p0 = Op0 + (size_t)row0 * CD;
    const short* p1 = Op1 + (size_t)row0 * CD;
    const short* p2 = Op2 + (size_t)row0 * CD;
    const short* p3 = Op3 + (size_t)row0 * CD;
    floatx4 acc[2][4];
#pragma unroll
    for (int rt = 0; rt < 2; ++rt)
#pragma unroll
        for (int j = 0; j < 4; ++j) acc[rt][j] = (floatx4){0.f, 0.f, 0.f, 0.f};
#pragma unroll
    for (int c = 0; c < 8; ++c) {
        int off0 = c * 32 + q * 8, off1 = 16 * CD + c * 32 + q * 8;
        short8 x0 = ld8(p0 + off0), y0 = ld8(p1 + off0);
        short8 x1 = ld8(p0 + off1), y1 = ld8(p1 + off1);
        float f0[8], f1[8];
#pragma unroll
        for (int jj = 0; jj < 8; ++jj) {
            f0[jj] = bf2f(x0[jj]) + bf2f(y0[jj]);
            f1[jj] = bf2f(x1[jj]) + bf2f(y1[jj]);
        }
        if (nks >= 3) {
            short8 z0 = ld8(p2 + off0), z1 = ld8(p2 + off1);
#pragma unroll
            for (int jj = 0; jj < 8; ++jj) {
                f0[jj] += bf2f(z0[jj]);
                f1[jj] += bf2f(z1[jj]);
            }
        }
        if (nks >= 4) {
            short8 u0 = ld8(p3 + off0), u1 = ld8(p3 + off1);
#pragma unroll
            for (int jj = 0; jj < 8; ++jj) {
                f0[jj] += bf2f(u0[jj]);
                f1[jj] += bf2f(u1[jj]);
            }
        }
        short8 af0, af1;
#pragma unroll
        for (int jj = 0; jj < 8; ++jj) {
            af0[jj] = bf16s(f0[jj] * inv0);
            af1[jj] = bf16s(f1[jj] * inv1);
        }
#pragma unroll
        for (int j = 0; j < 4; ++j) {
            short8 wf = ld8(&Ws[j * 4096 + c * 512 + l * 8]);
            acc[0][j] = mfma16(af0, wf, acc[0][j]);
            acc[1][j] = mfma16(af1, wf, acc[1][j]);
        }
    }
#pragma unroll
    for (int rt = 0; rt < 2; ++rt)
#pragma unroll
        for (int j = 0; j < 4; ++j) {
            int col = n0 + j * 16 + r;
            float bvv = bo[col];
#pragma unroll
            for (int i = 0; i < 4; ++i)
                out[(size_t)(m0 + w * 32 + rt * 16 + q * 4 + i) * CD + col] =
                    acc[rt][j][i] + bvv;
        }
}

extern "C" void kernel_launch(void* const* d_in, const int* in_sizes, int n_in,
                              void* d_out, int out_size, void* d_ws, size_t ws_size,
                              hipStream_t stream) {
    const float* x  = (const float*)d_in[0];
    const float* Wq = (const float*)d_in[1];
    const float* bq = (const float*)d_in[2];
    const float* Wk = (const float*)d_in[3];
    const float* bk = (const float*)d_in[4];
    const float* Wv = (const float*)d_in[5];
    const float* bv = (const float*)d_in[6];
    const float* Wo = (const float*)d_in[7];
    const float* bo = (const float*)d_in[8];
    float* out = (float*)d_out;

    char* ws = (char*)d_ws;
    const size_t MB = 1024u * 1024u;
    short* xb  = (short*)(ws);             // 8 MB: x bf16; DEAD after proj3 ->
    short* Op0 = (short*)(ws);             //        reused as partial-O (ks=0)
    short* Qb  = (short*)(ws + 8 * MB);    // 8 MB: Q*scale bf16
    short* Kb  = (short*)(ws + 16 * MB);   // 8 MB: K bf16
    short* Vt  = (short*)(ws + 24 * MB);   // 8 MB: V^T bf16 [4][256][4096]
    short* Op1 = (short*)(ws + 32 * MB);   // 8 MB: partial-O (ks=1)
    short* Wt  = (short*)(ws + 40 * MB);   // 512 KB: transposed weights bf16
    float* Lp  = (float*)(ws + 40 * MB + 512 * 1024);  // 256 KB: partial l [4][16384]

    // 4-way split-K (1024 blocks = 4/CU) when workspace permits; else 3/2.
    int nks = (ws_size >= 57 * MB) ? 4
            : (ws_size >= 49 * MB + 512 * 1024) ? 3 : 2;
    short* Op2 = (nks >= 3) ? (short*)(ws + 41 * MB) : Op1;
    short* Op3 = (nks >= 4) ? (short*)(ws + 49 * MB) : Op1;

    k_convx<<<dim3(MTOT * CD / (256 * 4)), 256, 0, stream>>>(x, xb);
    k_convw<<<dim3(256, 4), 256, 0, stream>>>(Wq, Wk, Wv, Wo, Wt);
    k_proj3<<<dim3(1536), 256, 0, stream>>>(xb, Wt, bq, bk, bv, Qb, Kb, Vt);
    k_attn<<<dim3(64 * NB * nks), 256, 0, stream>>>(Qb, Kb, Vt, Op0, Op1, Op2, Op3, Lp, nks);
    k_oproj<<<dim3(512), 256, 0, stream>>>(Op0, Op1, Op2, Op3, Lp, Wt + 196608, bo, out, nks);
}

// Round 6
// 271.576 us; speedup vs baseline: 1.2562x; 1.2562x over previous
//
#include <hip/hip_runtime.h>
#include <hip/hip_bf16.h>

// SpatialAttention: B=4, H=W=64, C=D=256. N=4096 tokens/batch.
// fp32->bf16, QKV proj (MFMA, W staged in LDS), split-K flash attn with
// SWAPPED QK. v6 = v1's proven kernel config (BM=64, BN=32, 4 waves,
// nks=3, launch_bounds(256,3) -> NO spill, 84 VGPR) + XCD cohort swizzle
// (v5-proven: FETCH 70->32 MB) + cvt_pk P packing (v4-proven neutral+).
// v5's regression was solely the launch_bounds(256,4) VGPR cap (64 regs,
// acc spill -> 221 MB scratch writes); this reverts that while keeping
// the read-locality win. No-max softmax => unnormalized partials;
// combine folded into out-proj.

typedef __attribute__((ext_vector_type(8))) short short8;
typedef __attribute__((ext_vector_type(4))) short short4v;
typedef __attribute__((ext_vector_type(4))) float floatx4;

#define NB 4
#define NT 4096
#define CD 256
#define MTOT (NB * NT)   // 16384

__device__ __forceinline__ short bf16s(float f) {
    union { float f; unsigned u; } a; a.f = f;
    unsigned u = a.u;
    return (short)((u + 0x7fffu + ((u >> 16) & 1u)) >> 16);   // RNE
}

__device__ __forceinline__ float bf2f(short s) {
    union { unsigned u; float f; } a;
    a.u = ((unsigned)(unsigned short)s) << 16;
    return a.f;
}

__device__ __forceinline__ short8 ld8(const short* p) {
    return *(const short8*)p;
}

__device__ __forceinline__ floatx4 mfma16(short8 a, short8 b, floatx4 c) {
    return __builtin_amdgcn_mfma_f32_16x16x32_bf16(a, b, c, 0, 0, 0);
}

// async global->LDS DMA, 16 B/lane; LDS dest = wave-uniform base + lane*16
__device__ __forceinline__ void dma16(const void* g, void* l) {
    __builtin_amdgcn_global_load_lds(
        (const __attribute__((address_space(1))) void*)g,
        (__attribute__((address_space(3))) void*)l, 16, 0, 0);
}

// ---- convert features fp32 -> bf16 [16384 x 256] row-major ----
__global__ __launch_bounds__(256) void k_convx(const float* __restrict__ x,
                                               short* __restrict__ xb) {
    int i = (blockIdx.x * 256 + threadIdx.x) * 4;
    float4 v = *(const float4*)(x + i);
    short4v o;
    o.x = bf16s(v.x); o.y = bf16s(v.y); o.z = bf16s(v.z); o.w = bf16s(v.w);
    *(short4v*)(xb + i) = o;
}

// ---- convert + transpose weights: Wt[z][n][c] = W_z[c][n], bf16 ----
__global__ __launch_bounds__(256) void k_convw(const float* __restrict__ w0,
                                               const float* __restrict__ w1,
                                               const float* __restrict__ w2,
                                               const float* __restrict__ w3,
                                               short* __restrict__ wt) {
    int z = blockIdx.y;
    const float* w = (z == 0) ? w0 : (z == 1) ? w1 : (z == 2) ? w2 : w3;
    int c = blockIdx.x;
    int n = threadIdx.x;
    wt[z * 65536 + n * 256 + c] = bf16s(w[c * 256 + n]);
}

// ---- fused QKV projection: 1536 blocks 1-D, XCD-swizzled so the 12
// blocks (3 z x 4 y) sharing one 128-row xb slab land on one XCD ----
__global__ __launch_bounds__(256) void k_proj3(const short* __restrict__ A,
                                               const short* __restrict__ Wt,
                                               const float* __restrict__ bq,
                                               const float* __restrict__ bk,
                                               const float* __restrict__ bv,
                                               short* __restrict__ Qb,
                                               short* __restrict__ Kb,
                                               short* __restrict__ Vt) {
    __shared__ __align__(16) short Ws[16384];
    int blk = blockIdx.x;                       // 1536 blocks
    int wk = (blk & 7) * 192 + (blk >> 3);      // xcd = blk%8 gets work chunk
    int m = wk / 12, rest = wk - m * 12;        // work = m*12 + z*4 + y
    int z = rest >> 2, y = rest & 3;
    const short* W = Wt + z * 65536;
    const float* bias = (z == 0) ? bq : (z == 1) ? bk : bv;
    float scale = (z == 0) ? 0.0625f : 1.0f;   // fold 1/sqrt(256) into Q
    int m0 = m * 128;
    int n0 = y * 64;
    int tid = threadIdx.x;
    int w = tid >> 6, l = tid & 63, r = l & 15, q = l >> 4;

#pragma unroll
    for (int cg = 0; cg < 8; ++cg)
        dma16(W + (size_t)(n0 + w * 16 + r) * CD + (cg * 4 + q) * 8,
              &Ws[w * 4096 + cg * 512]);
    __syncthreads();

    const short* a0 = A + (size_t)(m0 + w * 32 + r) * CD;
    const short* a1 = a0 + 16 * CD;
    floatx4 acc[2][4];
#pragma unroll
    for (int rt = 0; rt < 2; ++rt)
#pragma unroll
        for (int j = 0; j < 4; ++j) acc[rt][j] = (floatx4){0.f, 0.f, 0.f, 0.f};
#pragma unroll
    for (int c = 0; c < 8; ++c) {
        short8 af0 = ld8(a0 + c * 32 + q * 8);
        short8 af1 = ld8(a1 + c * 32 + q * 8);
#pragma unroll
        for (int j = 0; j < 4; ++j) {
            short8 wf = ld8(&Ws[j * 4096 + c * 512 + l * 8]);
            acc[0][j] = mfma16(af0, wf, acc[0][j]);
            acc[1][j] = mfma16(af1, wf, acc[1][j]);
        }
    }
#pragma unroll
    for (int rt = 0; rt < 2; ++rt)
#pragma unroll
        for (int j = 0; j < 4; ++j) {
            int col = n0 + j * 16 + r;
            float bvv = bias[col];
#pragma unroll
            for (int i = 0; i < 4; ++i) {
                int row = m0 + w * 32 + rt * 16 + q * 4 + i;
                short s = bf16s((acc[rt][j][i] + bvv) * scale);
                if (z == 0) Qb[(size_t)row * CD + col] = s;
                else if (z == 1) Kb[(size_t)row * CD + col] = s;
                else {
                    int bb = row >> 12, lm = row & (NT - 1);
                    Vt[((size_t)bb * CD + col) * NT + lm] = s;
                }
            }
        }
}

// ---- split-K flash attention v6: v1 loop + 1-D XCD-swizzled grid ----
// Works ordered cohort-major: work = (b*nks+ks)*64 + x, so each XCD owns
// whole cohorts; a cohort's 64 blocks stream the SAME 0.5 MB K-slab and
// 0.5 MB V-slab in the same iteration order -> L2-resident KV
// (v5 measured: FETCH_SIZE 70 -> 32 MB).
__global__ __launch_bounds__(256, 3) void k_attn(const short* __restrict__ Qb,
                                                 const short* __restrict__ Kb,
                                                 const short* __restrict__ Vt,
                                                 short* __restrict__ Op0,
                                                 short* __restrict__ Op1,
                                                 short* __restrict__ Op2,
                                                 float* __restrict__ Lp,
                                                 int nks) {
    __shared__ __align__(16) short Ks[2][8192];   // 2 x 16 KB
    __shared__ __align__(16) short P[64][36];     // [row][tok], pad 4

    const int tid = threadIdx.x;
    const int w = tid >> 6;
    const int l = tid & 63;
    const int r = l & 15, q = l >> 4;
    // 1-D swizzled decode: nbk = 64*NB*nks, nbk % 8 == 0 -> bijective
    const int nbk = gridDim.x;
    const int blk = blockIdx.x;
    const int wk = (blk & 7) * (nbk >> 3) + (blk >> 3);
    const int bx = wk & 63;          // x fastest within cohort
    const int co = wk >> 6;          // cohort = b*nks + ks
    const int b = co / nks;
    const int ks = co - b * nks;
    const int m0 = bx * 64;
    // token range: 128 units of 32 tokens split across nks
    const int qq = 128 / nks, rem = 128 % nks;
    const int u0 = ks * qq + (ks < rem ? ks : rem);
    const int cnt = qq + (ks < rem ? 1 : 0);
    const int t0 = u0 * 32;
    const int tt_d = w & 1;               // DMA token-subtile
    const int cb_d = (w >> 1) * 4;        // DMA chunk-group base
    const short* Qp = Qb + (size_t)b * NT * CD;
    const short* Kp = Kb + (size_t)b * NT * CD;
    const short* Vp = Vt + (size_t)b * CD * NT;   // [256][4096]
    short* Op = (ks == 0) ? Op0 : (ks == 1) ? Op1 : Op2;

    // Q fragments (B-operand): rows m0 + w*16 + r, Q pre-scaled by 1/16
    short8 qf[8];
#pragma unroll
    for (int c = 0; c < 8; ++c)
        qf[c] = ld8(Qp + (size_t)(m0 + w * 16 + r) * CD + c * 32 + q * 8);

    floatx4 o[4][4];
#pragma unroll
    for (int rt = 0; rt < 4; ++rt)
#pragma unroll
        for (int dt = 0; dt < 4; ++dt) o[rt][dt] = (floatx4){0.f, 0.f, 0.f, 0.f};
    float ls = 0.f;

    // prologue: DMA K tile 0 into Ks[0]
#pragma unroll
    for (int j = 0; j < 4; ++j)
        dma16(Kp + (size_t)(t0 + tt_d * 16 + r) * CD + ((cb_d + j) * 4 + q) * 8,
              &Ks[0][tt_d * 4096 + (cb_d + j) * 512]);

#pragma unroll 1
    for (int it = 0; it < cnt; ++it) {
        const int p = it & 1;
        const int n0 = t0 + it * 32;
        __syncthreads();   // drains vmcnt(0): Ks[p] DMA complete, P consumed

        // V fragments for THIS iter (before next DMA so their wait leaves DMA in flight)
        short8 vf[4];
#pragma unroll
        for (int dt = 0; dt < 4; ++dt)
            vf[dt] = ld8(Vp + (size_t)(w * 64 + dt * 16 + r) * NT + n0 + q * 8);

        if (it + 1 < cnt) {
#pragma unroll
            for (int j = 0; j < 4; ++j)
                dma16(Kp + (size_t)(n0 + 32 + tt_d * 16 + r) * CD + ((cb_d + j) * 4 + q) * 8,
                      &Ks[1 - p][tt_d * 4096 + (cb_d + j) * 512]);
        }

        // QK swapped: S^T tiles; lane (r,q) reg i = S[row m0+w*16+r][tok n0+tt*16+q*4+i]
        floatx4 s0 = {0.f, 0.f, 0.f, 0.f};
        floatx4 s1 = {0.f, 0.f, 0.f, 0.f};
#pragma unroll
        for (int c = 0; c < 8; ++c) {
            s0 = mfma16(ld8(&Ks[p][c * 512 + l * 8]), qf[c], s0);
            s1 = mfma16(ld8(&Ks[p][4096 + c * 512 + l * 8]), qf[c], s1);
        }

        // exp + scalar lsum + packed cvt_pk b64 P writes (4 bf16 each)
#pragma unroll
        for (int tt = 0; tt < 2; ++tt) {
            floatx4 sv = tt ? s1 : s0;
            float e0 = __expf(sv[0]), e1 = __expf(sv[1]);
            float e2 = __expf(sv[2]), e3 = __expf(sv[3]);
            ls += (e0 + e1) + (e2 + e3);
            unsigned pk01, pk23;
            asm("v_cvt_pk_bf16_f32 %0, %1, %2" : "=v"(pk01) : "v"(e0), "v"(e1));
            asm("v_cvt_pk_bf16_f32 %0, %1, %2" : "=v"(pk23) : "v"(e2), "v"(e3));
            uint2 pk; pk.x = pk01; pk.y = pk23;
            *(uint2*)&P[w * 16 + r][tt * 16 + q * 4] = pk;
        }
        // P visible block-wide; NOT __syncthreads (would drain the K DMA)
        asm volatile("s_waitcnt lgkmcnt(0)\n\ts_barrier" ::: "memory");

        // PV: o[rt][dt] += P[rt rows][tok] x V[d-slice][tok]
#pragma unroll
        for (int rt = 0; rt < 4; ++rt) {
            short8 pf = ld8(&P[rt * 16 + r][q * 8]);
#pragma unroll
            for (int dt = 0; dt < 4; ++dt)
                o[rt][dt] = mfma16(pf, vf[dt], o[rt][dt]);
        }
    }

    // partial lsum: lane (r,q) holds row m0+w*16+r partial; reduce across q
    ls += __shfl_xor(ls, 16);
    ls += __shfl_xor(ls, 32);
    if (l < 16)
        Lp[(size_t)ks * MTOT + b * NT + m0 + w * 16 + l] = ls;

    // unnormalized partial O store (cols w*64..+64, all 64 rows)
#pragma unroll
    for (int rt = 0; rt < 4; ++rt)
#pragma unroll
        for (int i = 0; i < 4; ++i) {
            int row = m0 + rt * 16 + q * 4 + i;
#pragma unroll
            for (int dt = 0; dt < 4; ++dt)
                Op[((size_t)b * NT + row) * CD + w * 64 + dt * 16 + r] =
                    bf16s(o[rt][dt][i]);
        }
}

// ---- output projection + split-K combine: A = (sum Opk)/(sum lk), fp32 out
// 512 blocks 1-D, XCD-swizzled so the 4 y-blocks sharing one 128-row
// partial slab land on one XCD (partials read from L2 after first touch).
__global__ __launch_bounds__(256) void k_oproj(const short* __restrict__ Op0,
                                               const short* __restrict__ Op1,
                                               const short* __restrict__ Op2,
                                               const float* __restrict__ Lp,
                                               const short* __restrict__ Wot,
                                               const float* __restrict__ bo,
                                               float* __restrict__ out, int nks) {
    __shared__ __align__(16) short Ws[16384];
    int blk = blockIdx.x;                       // 512 blocks
    int wk = (blk & 7) * 64 + (blk >> 3);       // work = m*4 + y
    int m0 = (wk >> 2) * 128;
    int n0 = (wk & 3) * 64;
    int tid = threadIdx.x;
    int w = tid >> 6, l = tid & 63, r = l & 15, q = l >> 4;

#pragma unroll
    for (int cg = 0; cg < 8; ++cg)
        dma16(Wot + (size_t)(n0 + w * 16 + r) * CD + (cg * 4 + q) * 8,
              &Ws[w * 4096 + cg * 512]);
    __syncthreads();

    int row0 = m0 + w * 32 + r;
    float lt0 = Lp[row0] + Lp[MTOT + row0];
    float lt1 = Lp[row0 + 16] + Lp[MTOT + row0 + 16];
    if (nks == 3) { lt0 += Lp[2 * (size_t)MTOT + row0]; lt1 += Lp[2 * (size_t)MTOT + row0 + 16]; }
    float inv0 = 1.0f / lt0, inv1 = 1.0f / lt1;
    const short* p0 = Op0 + (size_t)row0 * CD;
    const short* p1 = Op1 + (size_t)row0 * CD;
    const short* p2 = Op2 + (size_t)row0 * CD;
    floatx4 acc[2][4];
#pragma unroll
    for (int rt = 0; rt < 2; ++rt)
#pragma unroll
        for (int j = 0; j < 4; ++j) acc[rt][j] = (floatx4){0.f, 0.f, 0.f, 0.f};
#pragma unroll
    for (int c = 0; c < 8; ++c) {
        int off0 = c * 32 + q * 8, off1 = 16 * CD + c * 32 + q * 8;
        short8 x0 = ld8(p0 + off0), y0 = ld8(p1 + off0);
        short8 x1 = ld8(p0 + off1), y1 = ld8(p1 + off1);
        short8 af0, af1;
        if (nks == 3) {
            short8 z0 = ld8(p2 + off0), z1 = ld8(p2 + off1);
#pragma unroll
            for (int jj = 0; jj < 8; ++jj) {
                af0[jj] = bf16s((bf2f(x0[jj]) + bf2f(y0[jj]) + bf2f(z0[jj])) * inv0);
                af1[jj] = bf16s((bf2f(x1[jj]) + bf2f(y1[jj]) + bf2f(z1[jj])) * inv1);
            }
        } else {
#pragma unroll
            for (int jj = 0; jj < 8; ++jj) {
                af0[jj] = bf16s((bf2f(x0[jj]) + bf2f(y0[jj])) * inv0);
                af1[jj] = bf16s((bf2f(x1[jj]) + bf2f(y1[jj])) * inv1);
            }
        }
#pragma unroll
        for (int j = 0; j < 4; ++j) {
            short8 wf = ld8(&Ws[j * 4096 + c * 512 + l * 8]);
            acc[0][j] = mfma16(af0, wf, acc[0][j]);
            acc[1][j] = mfma16(af1, wf, acc[1][j]);
        }
    }
#pragma unroll
    for (int rt = 0; rt < 2; ++rt)
#pragma unroll
        for (int j = 0; j < 4; ++j) {
            int col = n0 + j * 16 + r;
            float bvv = bo[col];
#pragma unroll
            for (int i = 0; i < 4; ++i)
                out[(size_t)(m0 + w * 32 + rt * 16 + q * 4 + i) * CD + col] =
                    acc[rt][j][i] + bvv;
        }
}

extern "C" void kernel_launch(void* const* d_in, const int* in_sizes, int n_in,
                              void* d_out, int out_size, void* d_ws, size_t ws_size,
                              hipStream_t stream) {
    const float* x  = (const float*)d_in[0];
    const float* Wq = (const float*)d_in[1];
    const float* bq = (const float*)d_in[2];
    const float* Wk = (const float*)d_in[3];
    const float* bk = (const float*)d_in[4];
    const float* Wv = (const float*)d_in[5];
    const float* bv = (const float*)d_in[6];
    const float* Wo = (const float*)d_in[7];
    const float* bo = (const float*)d_in[8];
    float* out = (float*)d_out;

    char* ws = (char*)d_ws;
    const size_t MB = 1024u * 1024u;
    short* xb  = (short*)(ws);             // 8 MB: x bf16; DEAD after proj3 ->
    short* Op0 = (short*)(ws);             //        reused as partial-O (ks=0)
    short* Qb  = (short*)(ws + 8 * MB);    // 8 MB: Q*scale bf16
    short* Kb  = (short*)(ws + 16 * MB);   // 8 MB: K bf16
    short* Vt  = (short*)(ws + 24 * MB);   // 8 MB: V^T bf16 [4][256][4096]
    short* Op1 = (short*)(ws + 32 * MB);   // 8 MB: partial-O (ks=1)
    short* Wt  = (short*)(ws + 40 * MB);   // 512 KB: transposed weights bf16
    float* Lp  = (float*)(ws + 40 * MB + 512 * 1024);  // 192 KB: partial l [3][16384]
    short* Op2 = (short*)(ws + 41 * MB);   // 8 MB: partial-O (ks=2), if ws allows

    // 3-way split-K (768 blocks = 3/CU) when workspace permits, else 2-way.
    int nks = (ws_size >= 49 * MB + 512 * 1024) ? 3 : 2;
    if (nks == 2) Op2 = Op1;   // unused, keep pointer valid

    k_convx<<<dim3(MTOT * CD / (256 * 4)), 256, 0, stream>>>(x, xb);
    k_convw<<<dim3(256, 4), 256, 0, stream>>>(Wq, Wk, Wv, Wo, Wt);
    k_proj3<<<dim3(1536), 256, 0, stream>>>(xb, Wt, bq, bk, bv, Qb, Kb, Vt);
    k_attn<<<dim3(64 * NB * nks), 256, 0, stream>>>(Qb, Kb, Vt, Op0, Op1, Op2, Lp, nks);
    k_oproj<<<dim3(512), 256, 0, stream>>>(Op0, Op1, Op2, Lp, Wt + 196608, bo, out, nks);
}

// Round 7
// 269.447 us; speedup vs baseline: 1.2661x; 1.0079x over previous
//
#include <hip/hip_runtime.h>
#include <hip/hip_bf16.h>

// SpatialAttention: B=4, H=W=64, C=D=256. N=4096 tokens/batch.
// fp32->bf16, QKV proj (MFMA, W staged in LDS), split-K flash attn with
// SWAPPED QK. v7 = v1 dataflow with BN=64 per iteration and only TWO
// barrier intervals per 64 tokens (v1 had four): single-buffered 32 KB
// K tile (DMA re-fill issued right after the P-barrier, overwrite-safe
// because all QK reads completed at that barrier; drained by the next
// __syncthreads), P[64][68] single-buffered, QK in two tt-substeps,
// V loaded in two halves (va at top, vb post-barrier). Evidence basis:
// v2-v6 falsified LDS-volume/drain/locality theories; time tracks
// barrier-interval count (alignment overhead dominates). Keeps v6's
// proven attn cohort swizzle (FETCH 70->19 MB) + cvt_pk P packing;
// reverts proj/oproj to v1 2-D forms (v6 cost ~11 us there). No-max
// softmax => unnormalized partials; combine folded into out-proj.

typedef __attribute__((ext_vector_type(8))) short short8;
typedef __attribute__((ext_vector_type(4))) short short4v;
typedef __attribute__((ext_vector_type(4))) float floatx4;

#define NB 4
#define NT 4096
#define CD 256
#define MTOT (NB * NT)   // 16384

__device__ __forceinline__ short bf16s(float f) {
    union { float f; unsigned u; } a; a.f = f;
    unsigned u = a.u;
    return (short)((u + 0x7fffu + ((u >> 16) & 1u)) >> 16);   // RNE
}

__device__ __forceinline__ float bf2f(short s) {
    union { unsigned u; float f; } a;
    a.u = ((unsigned)(unsigned short)s) << 16;
    return a.f;
}

__device__ __forceinline__ short8 ld8(const short* p) {
    return *(const short8*)p;
}

__device__ __forceinline__ floatx4 mfma16(short8 a, short8 b, floatx4 c) {
    return __builtin_amdgcn_mfma_f32_16x16x32_bf16(a, b, c, 0, 0, 0);
}

// async global->LDS DMA, 16 B/lane; LDS dest = wave-uniform base + lane*16
__device__ __forceinline__ void dma16(const void* g, void* l) {
    __builtin_amdgcn_global_load_lds(
        (const __attribute__((address_space(1))) void*)g,
        (__attribute__((address_space(3))) void*)l, 16, 0, 0);
}

// ---- convert features fp32 -> bf16 [16384 x 256] row-major ----
__global__ __launch_bounds__(256) void k_convx(const float* __restrict__ x,
                                               short* __restrict__ xb) {
    int i = (blockIdx.x * 256 + threadIdx.x) * 4;
    float4 v = *(const float4*)(x + i);
    short4v o;
    o.x = bf16s(v.x); o.y = bf16s(v.y); o.z = bf16s(v.z); o.w = bf16s(v.w);
    *(short4v*)(xb + i) = o;
}

// ---- convert + transpose weights: Wt[z][n][c] = W_z[c][n], bf16 ----
__global__ __launch_bounds__(256) void k_convw(const float* __restrict__ w0,
                                               const float* __restrict__ w1,
                                               const float* __restrict__ w2,
                                               const float* __restrict__ w3,
                                               short* __restrict__ wt) {
    int z = blockIdx.y;
    const float* w = (z == 0) ? w0 : (z == 1) ? w1 : (z == 2) ? w2 : w3;
    int c = blockIdx.x;
    int n = threadIdx.x;
    wt[z * 65536 + n * 256 + c] = bf16s(w[c * 256 + n]);
}

// ---- fused QKV projection: block = 256 thr = 4 waves, 128m x 64n tile ----
__global__ __launch_bounds__(256) void k_proj3(const short* __restrict__ A,
                                               const short* __restrict__ Wt,
                                               const float* __restrict__ bq,
                                               const float* __restrict__ bk,
                                               const float* __restrict__ bv,
                                               short* __restrict__ Qb,
                                               short* __restrict__ Kb,
                                               short* __restrict__ Vt) {
    __shared__ __align__(16) short Ws[16384];
    int z = blockIdx.z;
    const short* W = Wt + z * 65536;
    const float* bias = (z == 0) ? bq : (z == 1) ? bk : bv;
    float scale = (z == 0) ? 0.0625f : 1.0f;   // fold 1/sqrt(256) into Q
    int m0 = blockIdx.x * 128;
    int n0 = blockIdx.y * 64;
    int tid = threadIdx.x;
    int w = tid >> 6, l = tid & 63, r = l & 15, q = l >> 4;

#pragma unroll
    for (int cg = 0; cg < 8; ++cg)
        dma16(W + (size_t)(n0 + w * 16 + r) * CD + (cg * 4 + q) * 8,
              &Ws[w * 4096 + cg * 512]);
    __syncthreads();

    const short* a0 = A + (size_t)(m0 + w * 32 + r) * CD;
    const short* a1 = a0 + 16 * CD;
    floatx4 acc[2][4];
#pragma unroll
    for (int rt = 0; rt < 2; ++rt)
#pragma unroll
        for (int j = 0; j < 4; ++j) acc[rt][j] = (floatx4){0.f, 0.f, 0.f, 0.f};
#pragma unroll
    for (int c = 0; c < 8; ++c) {
        short8 af0 = ld8(a0 + c * 32 + q * 8);
        short8 af1 = ld8(a1 + c * 32 + q * 8);
#pragma unroll
        for (int j = 0; j < 4; ++j) {
            short8 wf = ld8(&Ws[j * 4096 + c * 512 + l * 8]);
            acc[0][j] = mfma16(af0, wf, acc[0][j]);
            acc[1][j] = mfma16(af1, wf, acc[1][j]);
        }
    }
#pragma unroll
    for (int rt = 0; rt < 2; ++rt)
#pragma unroll
        for (int j = 0; j < 4; ++j) {
            int col = n0 + j * 16 + r;
            float bvv = bias[col];
#pragma unroll
            for (int i = 0; i < 4; ++i) {
                int row = m0 + w * 32 + rt * 16 + q * 4 + i;
                short s = bf16s((acc[rt][j][i] + bvv) * scale);
                if (z == 0) Qb[(size_t)row * CD + col] = s;
                else if (z == 1) Kb[(size_t)row * CD + col] = s;
                else {
                    int bb = row >> 12, lm = row & (NT - 1);
                    Vt[((size_t)bb * CD + col) * NT + lm] = s;
                }
            }
        }
}

// ---- split-K flash attention v7: BM=64, BN=64, 4 waves, 2 barriers/64tok ----
// 1-D XCD-swizzled grid (cohort-major: work = (b*nks+ks)*64 + x -> each
// XCD streams one K/V slab, L2-resident; v5/v6-proven FETCH 70->19 MB).
// Loop: __syncthreads (drains own K-DMA) -> va loads -> QK tt01 -> exp/P
// -> QK tt23 -> exp/P -> lgkm barrier -> K-DMA refill (overwrite-safe) ->
// vb loads -> PV half A -> PV half B.
__global__ __launch_bounds__(256, 3) void k_attn(const short* __restrict__ Qb,
                                                 const short* __restrict__ Kb,
                                                 const short* __restrict__ Vt,
                                                 short* __restrict__ Op0,
                                                 short* __restrict__ Op1,
                                                 short* __restrict__ Op2,
                                                 float* __restrict__ Lp,
                                                 int nks) {
    __shared__ __align__(16) short Ks[16384];     // 32 KB: 64 tok x 256 ch
    __shared__ __align__(16) short P[64][68];     // [row][tok 0..63], pad 4

    const int tid = threadIdx.x;
    const int w = tid >> 6;
    const int l = tid & 63;
    const int r = l & 15, q = l >> 4;
    // 1-D swizzled decode: nbk = 64*NB*nks, nbk % 8 == 0 -> bijective
    const int nbk = gridDim.x;
    const int blk = blockIdx.x;
    const int wk = (blk & 7) * (nbk >> 3) + (blk >> 3);
    const int bx = wk & 63;          // x fastest within cohort
    const int co = wk >> 6;          // cohort = b*nks + ks
    const int b = co / nks;
    const int ks = co - b * nks;
    const int m0 = bx * 64;
    // token range: 64 units of 64 tokens split across nks
    const int qq = 64 / nks, rem = 64 % nks;
    const int u0 = ks * qq + (ks < rem ? ks : rem);
    const int cnt = qq + (ks < rem ? 1 : 0);
    const int t0 = u0 * 64;
    const short* Qp = Qb + (size_t)b * NT * CD;
    const short* Kp = Kb + (size_t)b * NT * CD;
    const short* Vp = Vt + (size_t)b * CD * NT;   // [256][4096]
    short* Op = (ks == 0) ? Op0 : (ks == 1) ? Op1 : Op2;

    // Q fragments (B-operand): rows m0 + w*16 + r, Q pre-scaled by 1/16
    short8 qf[8];
#pragma unroll
    for (int c = 0; c < 8; ++c)
        qf[c] = ld8(Qp + (size_t)(m0 + w * 16 + r) * CD + c * 32 + q * 8);

    floatx4 o[4][4];
#pragma unroll
    for (int rt = 0; rt < 4; ++rt)
#pragma unroll
        for (int dt = 0; dt < 4; ++dt) o[rt][dt] = (floatx4){0.f, 0.f, 0.f, 0.f};
    float ls = 0.f;

    // prologue: DMA K tile 0 (64 tok); wave w stages tokens t0+w*16..+16
#pragma unroll
    for (int j = 0; j < 8; ++j)
        dma16(Kp + (size_t)(t0 + w * 16 + r) * CD + (j * 4 + q) * 8,
              &Ks[w * 4096 + j * 512]);

#pragma unroll 1
    for (int it = 0; it < cnt; ++it) {
        const int n0 = t0 + it * 64;
        __syncthreads();   // own vmcnt drain -> all K-DMA landed; P consumed

        // V fragments, first token-half (consumed at PV half A)
        short8 va[4];
#pragma unroll
        for (int dt = 0; dt < 4; ++dt)
            va[dt] = ld8(Vp + (size_t)(w * 64 + dt * 16 + r) * NT + n0 + q * 8);

        // QK token-half A (tt 0,1): lane (r,q) reg i =
        // S[row m0+w*16+r][tok n0+tt*16+q*4+i]
        {
            floatx4 s0 = {0.f, 0.f, 0.f, 0.f};
            floatx4 s1 = {0.f, 0.f, 0.f, 0.f};
#pragma unroll
            for (int c = 0; c < 8; ++c) {
                s0 = mfma16(ld8(&Ks[c * 512 + l * 8]), qf[c], s0);
                s1 = mfma16(ld8(&Ks[4096 + c * 512 + l * 8]), qf[c], s1);
            }
#pragma unroll
            for (int tt = 0; tt < 2; ++tt) {
                floatx4 sv = tt ? s1 : s0;
                float e0 = __expf(sv[0]), e1 = __expf(sv[1]);
                float e2 = __expf(sv[2]), e3 = __expf(sv[3]);
                ls += (e0 + e1) + (e2 + e3);
                unsigned pk01, pk23;
                asm("v_cvt_pk_bf16_f32 %0, %1, %2" : "=v"(pk01) : "v"(e0), "v"(e1));
                asm("v_cvt_pk_bf16_f32 %0, %1, %2" : "=v"(pk23) : "v"(e2), "v"(e3));
                uint2 pk; pk.x = pk01; pk.y = pk23;
                *(uint2*)&P[w * 16 + r][tt * 16 + q * 4] = pk;
            }
        }
        // QK token-half B (tt 2,3)
        {
            floatx4 s2 = {0.f, 0.f, 0.f, 0.f};
            floatx4 s3 = {0.f, 0.f, 0.f, 0.f};
#pragma unroll
            for (int c = 0; c < 8; ++c) {
                s2 = mfma16(ld8(&Ks[8192 + c * 512 + l * 8]), qf[c], s2);
                s3 = mfma16(ld8(&Ks[12288 + c * 512 + l * 8]), qf[c], s3);
            }
#pragma unroll
            for (int tt = 0; tt < 2; ++tt) {
                floatx4 sv = tt ? s3 : s2;
                float e0 = __expf(sv[0]), e1 = __expf(sv[1]);
                float e2 = __expf(sv[2]), e3 = __expf(sv[3]);
                ls += (e0 + e1) + (e2 + e3);
                unsigned pk01, pk23;
                asm("v_cvt_pk_bf16_f32 %0, %1, %2" : "=v"(pk01) : "v"(e0), "v"(e1));
                asm("v_cvt_pk_bf16_f32 %0, %1, %2" : "=v"(pk23) : "v"(e2), "v"(e3));
                uint2 pk; pk.x = pk01; pk.y = pk23;
                *(uint2*)&P[w * 16 + r][32 + tt * 16 + q * 4] = pk;
            }
        }

        // P visible block-wide + all Ks reads complete (LDS-only wait;
        // the prologue/refill DMAs are NOT drained here)
        asm volatile("s_waitcnt lgkmcnt(0)\n\ts_barrier" ::: "memory");

        // K-DMA refill into the SAME buffer: safe, every wave's QK reads
        // retired before the barrier; drained at next __syncthreads.
        if (it + 1 < cnt) {
#pragma unroll
            for (int j = 0; j < 8; ++j)
                dma16(Kp + (size_t)(n0 + 64 + w * 16 + r) * CD + (j * 4 + q) * 8,
                      &Ks[w * 4096 + j * 512]);
        }

        // V fragments, second token-half (consumed at PV half B, hidden
        // under PV half A's 16 MFMAs)
        short8 vb[4];
#pragma unroll
        for (int dt = 0; dt < 4; ++dt)
            vb[dt] = ld8(Vp + (size_t)(w * 64 + dt * 16 + r) * NT + n0 + 32 + q * 8);

        // PV half A: tokens n0..+32
#pragma unroll
        for (int rt = 0; rt < 4; ++rt) {
            short8 pf = ld8(&P[rt * 16 + r][q * 8]);
#pragma unroll
            for (int dt = 0; dt < 4; ++dt)
                o[rt][dt] = mfma16(pf, va[dt], o[rt][dt]);
        }
        // PV half B: tokens n0+32..+64
#pragma unroll
        for (int rt = 0; rt < 4; ++rt) {
            short8 pf = ld8(&P[rt * 16 + r][32 + q * 8]);
#pragma unroll
            for (int dt = 0; dt < 4; ++dt)
                o[rt][dt] = mfma16(pf, vb[dt], o[rt][dt]);
        }
    }

    // partial lsum: lane (r,q) holds row m0+w*16+r partial; reduce across q
    ls += __shfl_xor(ls, 16);
    ls += __shfl_xor(ls, 32);
    if (l < 16)
        Lp[(size_t)ks * MTOT + b * NT + m0 + w * 16 + l] = ls;

    // unnormalized partial O store (cols w*64..+64, all 64 rows)
#pragma unroll
    for (int rt = 0; rt < 4; ++rt)
#pragma unroll
        for (int i = 0; i < 4; ++i) {
            int row = m0 + rt * 16 + q * 4 + i;
#pragma unroll
            for (int dt = 0; dt < 4; ++dt)
                Op[((size_t)b * NT + row) * CD + w * 64 + dt * 16 + r] =
                    bf16s(o[rt][dt][i]);
        }
}

// ---- output projection + split-K combine: A = (sum Opk)/(sum lk), fp32 out
__global__ __launch_bounds__(256) void k_oproj(const short* __restrict__ Op0,
                                               const short* __restrict__ Op1,
                                               const short* __restrict__ Op2,
                                               const float* __restrict__ Lp,
                                               const short* __restrict__ Wot,
                                               const float* __restrict__ bo,
                                               float* __restrict__ out, int nks) {
    __shared__ __align__(16) short Ws[16384];
    int m0 = blockIdx.x * 128;
    int n0 = blockIdx.y * 64;
    int tid = threadIdx.x;
    int w = tid >> 6, l = tid & 63, r = l & 15, q = l >> 4;

#pragma unroll
    for (int cg = 0; cg < 8; ++cg)
        dma16(Wot + (size_t)(n0 + w * 16 + r) * CD + (cg * 4 + q) * 8,
              &Ws[w * 4096 + cg * 512]);
    __syncthreads();

    int row0 = m0 + w * 32 + r;
    float lt0 = Lp[row0] + Lp[MTOT + row0];
    float lt1 = Lp[row0 + 16] + Lp[MTOT + row0 + 16];
    if (nks == 3) { lt0 += Lp[2 * (size_t)MTOT + row0]; lt1 += Lp[2 * (size_t)MTOT + row0 + 16]; }
    float inv0 = 1.0f / lt0, inv1 = 1.0f / lt1;
    const short* p0 = Op0 + (size_t)row0 * CD;
    const short* p1 = Op1 + (size_t)row0 * CD;
    const short* p2 = Op2 + (size_t)row0 * CD;
    floatx4 acc[2][4];
#pragma unroll
    for (int rt = 0; rt < 2; ++rt)
#pragma unroll
        for (int j = 0; j < 4; ++j) acc[rt][j] = (floatx4){0.f, 0.f, 0.f, 0.f};
#pragma unroll
    for (int c = 0; c < 8; ++c) {
        int off0 = c * 32 + q * 8, off1 = 16 * CD + c * 32 + q * 8;
        short8 x0 = ld8(p0 + off0), y0 = ld8(p1 + off0);
        short8 x1 = ld8(p0 + off1), y1 = ld8(p1 + off1);
        short8 af0, af1;
        if (nks == 3) {
            short8 z0 = ld8(p2 + off0), z1 = ld8(p2 + off1);
#pragma unroll
            for (int jj = 0; jj < 8; ++jj) {
                af0[jj] = bf16s((bf2f(x0[jj]) + bf2f(y0[jj]) + bf2f(z0[jj])) * inv0);
                af1[jj] = bf16s((bf2f(x1[jj]) + bf2f(y1[jj]) + bf2f(z1[jj])) * inv1);
            }
        } else {
#pragma unroll
            for (int jj = 0; jj < 8; ++jj) {
                af0[jj] = bf16s((bf2f(x0[jj]) + bf2f(y0[jj])) * inv0);
                af1[jj] = bf16s((bf2f(x1[jj]) + bf2f(y1[jj])) * inv1);
            }
        }
#pragma unroll
        for (int j = 0; j < 4; ++j) {
            short8 wf = ld8(&Ws[j * 4096 + c * 512 + l * 8]);
            acc[0][j] = mfma16(af0, wf, acc[0][j]);
            acc[1][j] = mfma16(af1, wf, acc[1][j]);
        }
    }
#pragma unroll
    for (int rt = 0; rt < 2; ++rt)
#pragma unroll
        for (int j = 0; j < 4; ++j) {
            int col = n0 + j * 16 + r;
            float bvv = bo[col];
#pragma unroll
            for (int i = 0; i < 4; ++i)
                out[(size_t)(m0 + w * 32 + rt * 16 + q * 4 + i) * CD + col] =
                    acc[rt][j][i] + bvv;
        }
}

extern "C" void kernel_launch(void* const* d_in, const int* in_sizes, int n_in,
                              void* d_out, int out_size, void* d_ws, size_t ws_size,
                              hipStream_t stream) {
    const float* x  = (const float*)d_in[0];
    const float* Wq = (const float*)d_in[1];
    const float* bq = (const float*)d_in[2];
    const float* Wk = (const float*)d_in[3];
    const float* bk = (const float*)d_in[4];
    const float* Wv = (const float*)d_in[5];
    const float* bv = (const float*)d_in[6];
    const float* Wo = (const float*)d_in[7];
    const float* bo = (const float*)d_in[8];
    float* out = (float*)d_out;

    char* ws = (char*)d_ws;
    const size_t MB = 1024u * 1024u;
    short* xb  = (short*)(ws);             // 8 MB: x bf16; DEAD after proj3 ->
    short* Op0 = (short*)(ws);             //        reused as partial-O (ks=0)
    short* Qb  = (short*)(ws + 8 * MB);    // 8 MB: Q*scale bf16
    short* Kb  = (short*)(ws + 16 * MB);   // 8 MB: K bf16
    short* Vt  = (short*)(ws + 24 * MB);   // 8 MB: V^T bf16 [4][256][4096]
    short* Op1 = (short*)(ws + 32 * MB);   // 8 MB: partial-O (ks=1)
    short* Wt  = (short*)(ws + 40 * MB);   // 512 KB: transposed weights bf16
    float* Lp  = (float*)(ws + 40 * MB + 512 * 1024);  // 192 KB: partial l [3][16384]
    short* Op2 = (short*)(ws + 41 * MB);   // 8 MB: partial-O (ks=2), if ws allows

    // 3-way split-K (768 blocks = 3/CU) when workspace permits, else 2-way.
    int nks = (ws_size >= 49 * MB + 512 * 1024) ? 3 : 2;
    if (nks == 2) Op2 = Op1;   // unused, keep pointer valid

    k_convx<<<dim3(MTOT * CD / (256 * 4)), 256, 0, stream>>>(x, xb);
    k_convw<<<dim3(256, 4), 256, 0, stream>>>(Wq, Wk, Wv, Wo, Wt);
    k_proj3<<<dim3(MTOT / 128, CD / 64, 3), 256, 0, stream>>>(xb, Wt, bq, bk, bv, Qb, Kb, Vt);
    k_attn<<<dim3(64 * NB * nks), 256, 0, stream>>>(Qb, Kb, Vt, Op0, Op1, Op2, Lp, nks);
    k_oproj<<<dim3(MTOT / 128, CD / 64), 256, 0, stream>>>(Op0, Op1, Op2, Lp, Wt + 196608, bo, out, nks);
}